// Round 3
// baseline (774.661 us; speedup 1.0000x reference)
//
#include <hip/hip_runtime.h>
#include <cmath>

// x,y: (16,3,512,512) f32. Fused separable-Gaussian SSIM, scalar mean output.
// Row-streaming band kernel: v-conv in registers, h-conv via 21KB LDS row buffer.
constexpr int IMG_H = 512;
constexpr int IMG_W = 512;
constexpr int PLANES = 48;
constexpr int R_OUT = 32;               // output rows per block
constexpr int BANDS = IMG_H / R_OUT;    // 16
constexpr int NITER = R_OUT + 10;       // 42 input rows per band (±5 halo)
constexpr int PSTR = 528;               // padded row: value for col c at p=c+5; [0,522) used
constexpr long long TOTAL_PIX = (long long)PLANES * IMG_H * IMG_W;

struct GWin { float g[11]; };

__global__ __launch_bounds__(256, 3)
void ssim_band_kernel(const float* __restrict__ x,
                      const float* __restrict__ y,
                      double* __restrict__ accum,
                      GWin win)
{
    __shared__ __align__(16) float hbuf[2][5][PSTR];  // double-buffered v-conv rows, 5 fields
    __shared__ float wsum[4];

    const int tid   = threadIdx.x;
    const int band  = blockIdx.x & (BANDS - 1);
    const int plane = blockIdx.x >> 4;
    const int r0    = band * R_OUT;
    const int c0    = tid * 2;

    const float* __restrict__ xp = x + (size_t)plane * (IMG_H * IMG_W);
    const float* __restrict__ yp = y + (size_t)plane * (IMG_H * IMG_W);

    // zero the horizontal halo regions once: p in [0,5) and [517,528)
    for (int i = tid; i < 2 * 5 * 16; i += 256) {
        int w  = i & 15;
        int bf = i >> 4;
        int p  = (w < 5) ? w : (512 + w);   // 0..4 and 517..527
        hbuf[bf / 5][bf % 5][p] = 0.f;
    }
    // (covered by the first in-loop __syncthreads before any h-read)

    // 11-row register ring of {x,y,xx,yy,xy}, float2 per thread (2 columns)
    float2 xw[11], yw[11], xxw[11], yyw[11], xyw[11];
    float2 nx, ny;

    auto load2 = [&](const float* __restrict__ base, int i) -> float2 {
        int gr = r0 - 5 + i;
        if ((unsigned)gr < (unsigned)IMG_H)
            return *(const float2*)(base + (size_t)gr * IMG_W + c0);
        return make_float2(0.f, 0.f);
    };

    // prologue: fill slots 0..9 (iters 0..9), keep iter-10 row in nx/ny
    nx = load2(xp, 0);
    ny = load2(yp, 0);
#pragma unroll
    for (int i = 0; i < 10; ++i) {
        xw[i]  = nx;  yw[i]  = ny;
        xxw[i] = make_float2(nx.x * nx.x, nx.y * nx.y);
        yyw[i] = make_float2(ny.x * ny.x, ny.y * ny.y);
        xyw[i] = make_float2(nx.x * ny.x, nx.y * ny.y);
        nx = load2(xp, i + 1);
        ny = load2(yp, i + 1);
    }

    float lsum = 0.f;

#pragma unroll 1
    for (int jb = 0; jb < 33; jb += 11) {
#pragma unroll
        for (int rr = 0; rr < 11; ++rr) {
            const int j = jb + rr;        // output row index in band (uniform)
            if (j < R_OUT) {
                // push row (iter i = j+10) into ring slot (static index)
                const int s = (rr + 10) % 11;
                xw[s]  = nx;  yw[s]  = ny;
                xxw[s] = make_float2(nx.x * nx.x, nx.y * nx.y);
                yyw[s] = make_float2(ny.x * ny.x, ny.y * ny.y);
                xyw[s] = make_float2(nx.x * ny.x, nx.y * ny.y);
                // prefetch next row (hidden under this iter's compute)
                if (j + 11 < NITER) {
                    nx = load2(xp, j + 11);
                    ny = load2(yp, j + 11);
                }

                // vertical 11-tap conv, 5 fields, float2
                float2 vx{0,0}, vy{0,0}, vxx{0,0}, vyy{0,0}, vxy{0,0};
#pragma unroll
                for (int k = 0; k < 11; ++k) {
                    const int sk = (rr + k) % 11;   // static
                    const float g = win.g[k];
                    vx.x  += g * xw[sk].x;   vx.y  += g * xw[sk].y;
                    vy.x  += g * yw[sk].x;   vy.y  += g * yw[sk].y;
                    vxx.x += g * xxw[sk].x;  vxx.y += g * xxw[sk].y;
                    vyy.x += g * yyw[sk].x;  vyy.y += g * yyw[sk].y;
                    vxy.x += g * xyw[sk].x;  vxy.y += g * xyw[sk].y;
                }

                const int pb = j & 1;
                float* hb = &hbuf[pb][0][0];
                hb[0 * PSTR + 5 + c0] = vx.x;   hb[0 * PSTR + 6 + c0] = vx.y;
                hb[1 * PSTR + 5 + c0] = vy.x;   hb[1 * PSTR + 6 + c0] = vy.y;
                hb[2 * PSTR + 5 + c0] = vxx.x;  hb[2 * PSTR + 6 + c0] = vxx.y;
                hb[3 * PSTR + 5 + c0] = vyy.x;  hb[3 * PSTR + 6 + c0] = vyy.y;
                hb[4 * PSTR + 5 + c0] = vxy.x;  hb[4 * PSTR + 6 + c0] = vxy.y;

                __syncthreads();

                // horizontal 11-tap conv: 12-float window -> 2 outputs, 5 fields
                float m[5][2];
#pragma unroll
                for (int f = 0; f < 5; ++f) {
                    const float2* row2 = (const float2*)(hb + f * PSTR);
                    float2 a  = row2[tid];
                    float2 b2 = row2[tid + 1];
                    float2 c2 = row2[tid + 2];
                    float2 d2 = row2[tid + 3];
                    float2 e2 = row2[tid + 4];
                    float2 f2 = row2[tid + 5];
                    float w[12] = { a.x,  a.y,  b2.x, b2.y, c2.x, c2.y,
                                    d2.x, d2.y, e2.x, e2.y, f2.x, f2.y };
                    float s0 = 0.f, s1 = 0.f;
#pragma unroll
                    for (int k = 0; k < 11; ++k) {
                        s0 += win.g[k] * w[k];
                        s1 += win.g[k] * w[k + 1];
                    }
                    m[f][0] = s0;
                    m[f][1] = s1;
                }

#pragma unroll
                for (int u = 0; u < 2; ++u) {
                    float mx  = m[0][u];
                    float my  = m[1][u];
                    float mxx = m[2][u];
                    float myy = m[3][u];
                    float mxy = m[4][u];
                    float mu_x_sq = mx * mx;
                    float mu_y_sq = my * my;
                    float mu_xy   = mx * my;
                    float sig_x  = mxx - mu_x_sq;
                    float sig_y  = myy - mu_y_sq;
                    float sig_xy = mxy - mu_xy;
                    const float C1 = 0.01f * 0.01f;
                    const float C2 = 0.03f * 0.03f;
                    float n = (2.f * mu_xy + C1) * (2.f * sig_xy + C2);
                    float d = (mu_x_sq + mu_y_sq + C1) * (sig_x + sig_y + C2);
                    lsum += n / (d + 1e-8f);
                }
            }
        }
    }

    // block reduction
#pragma unroll
    for (int off = 32; off; off >>= 1) lsum += __shfl_down(lsum, off);
    if ((tid & 63) == 0) wsum[tid >> 6] = lsum;
    __syncthreads();
    if (tid == 0)
        atomicAdd(accum, (double)(wsum[0] + wsum[1] + wsum[2] + wsum[3]));
}

__global__ void ssim_finalize_kernel(const double* __restrict__ accum,
                                     float* __restrict__ out)
{
    out[0] = (float)(accum[0] / (double)TOTAL_PIX);
}

extern "C" void kernel_launch(void* const* d_in, const int* in_sizes, int n_in,
                              void* d_out, int out_size, void* d_ws, size_t ws_size,
                              hipStream_t stream) {
    const float* x = (const float*)d_in[0];
    const float* y = (const float*)d_in[1];
    float* out = (float*)d_out;
    double* accum = (double*)d_ws;

    GWin win;
    {
        double g[11], s = 0.0;
        for (int i = 0; i < 11; ++i) {
            double d = (double)i - 5.0;
            g[i] = std::exp(-(d * d) / (2.0 * 1.5 * 1.5));
            s += g[i];
        }
        for (int i = 0; i < 11; ++i) win.g[i] = (float)(g[i] / s);
    }

    hipMemsetAsync(d_ws, 0, sizeof(double), stream);

    const int nblocks = PLANES * BANDS;  // 768
    ssim_band_kernel<<<nblocks, 256, 0, stream>>>(x, y, accum, win);
    ssim_finalize_kernel<<<1, 1, 0, stream>>>(accum, out);
}

// Round 4
// 131.390 us; speedup vs baseline: 5.8959x; 5.8959x over previous
//
#include <hip/hip_runtime.h>
#include <cmath>

// x,y: (16,3,512,512) f32. Fused separable-Gaussian SSIM, scalar mean output.
// Row-streaming band kernel: slim x/y register ring (44 VGPR), products
// recomputed in the vertical conv, h-conv via 21KB double-buffered LDS row.
constexpr int IMG_H = 512;
constexpr int IMG_W = 512;
constexpr int PLANES = 48;
constexpr int R_OUT = 16;               // output rows per block
constexpr int BANDS = IMG_H / R_OUT;    // 32
constexpr int NITER = R_OUT + 10;       // 26 input rows per band
constexpr int PSTR = 528;               // padded row: col c stored at p=c+5
constexpr long long TOTAL_PIX = (long long)PLANES * IMG_H * IMG_W;

struct GWin { float g[11]; };

__global__ __launch_bounds__(256, 4)
void ssim_stream_kernel(const float* __restrict__ x,
                        const float* __restrict__ y,
                        double* __restrict__ accum,
                        GWin win)
{
    __shared__ __align__(16) float hbuf[2][5][PSTR];  // double-buffered v-conv row, 5 fields
    __shared__ float wsum[4];

    const int tid   = threadIdx.x;
    const int band  = blockIdx.x & (BANDS - 1);
    const int plane = blockIdx.x >> 5;
    const int r0    = band * R_OUT;
    const int c0    = tid * 2;

    const float* __restrict__ xp = x + (size_t)plane * (IMG_H * IMG_W);
    const float* __restrict__ yp = y + (size_t)plane * (IMG_H * IMG_W);

    // zero horizontal halo slots once: p in [0,5) and [517,528), both buffers, 5 fields
    for (int i = tid; i < 2 * 5 * 16; i += 256) {
        int w  = i & 15;
        int bf = i >> 4;
        int p  = (w < 5) ? w : (512 + w);   // 0..4, 517..527
        hbuf[bf / 5][bf % 5][p] = 0.f;
    }
    // (first in-loop __syncthreads orders these before any h-read)

    // 11-row register ring of x,y only — 44 VGPRs, explicit shift (static idx)
    float2 xw[11], yw[11];

    auto load2 = [&](const float* __restrict__ base, int i) -> float2 {
        int gr = r0 - 5 + i;
        if ((unsigned)gr < (unsigned)IMG_H)
            return *(const float2*)(base + (size_t)gr * IMG_W + c0);
        return make_float2(0.f, 0.f);
    };

    float2 nx = load2(xp, 0);
    float2 ny = load2(yp, 0);
#pragma unroll
    for (int i = 0; i < 10; ++i) {
        xw[i] = nx;  yw[i] = ny;
        nx = load2(xp, i + 1);
        ny = load2(yp, i + 1);
    }
    // nx,ny now hold input row 10

    float lsum = 0.f;

    for (int j = 0; j < R_OUT; ++j) {
        xw[10] = nx;  yw[10] = ny;

        // prefetch next input row (hidden under this row's compute)
        float2 px = make_float2(0.f, 0.f), py = px;
        if (j + 1 < R_OUT) {
            px = load2(xp, j + 11);
            py = load2(yp, j + 11);
        }

        // vertical 11-tap conv of {x,y,xx,yy,xy}; products recomputed (ring stays slim)
        float2 vx{0,0}, vy{0,0}, vxx{0,0}, vyy{0,0}, vxy{0,0};
#pragma unroll
        for (int k = 0; k < 11; ++k) {
            const float g = win.g[k];
            const float2 xv = xw[k], yv = yw[k];
            vx.x  += g * xv.x;          vx.y  += g * xv.y;
            vy.x  += g * yv.x;          vy.y  += g * yv.y;
            vxx.x += g * (xv.x * xv.x); vxx.y += g * (xv.y * xv.y);
            vyy.x += g * (yv.x * yv.x); vyy.y += g * (yv.y * yv.y);
            vxy.x += g * (xv.x * yv.x); vxy.y += g * (xv.y * yv.y);
        }

        // shift ring (static indices; compiler renames under unroll)
#pragma unroll
        for (int k = 0; k < 10; ++k) { xw[k] = xw[k + 1]; yw[k] = yw[k + 1]; }
        nx = px;  ny = py;

        float* hb = &hbuf[j & 1][0][0];
        hb[0 * PSTR + 5 + c0] = vx.x;   hb[0 * PSTR + 6 + c0] = vx.y;
        hb[1 * PSTR + 5 + c0] = vy.x;   hb[1 * PSTR + 6 + c0] = vy.y;
        hb[2 * PSTR + 5 + c0] = vxx.x;  hb[2 * PSTR + 6 + c0] = vxx.y;
        hb[3 * PSTR + 5 + c0] = vyy.x;  hb[3 * PSTR + 6 + c0] = vyy.y;
        hb[4 * PSTR + 5 + c0] = vxy.x;  hb[4 * PSTR + 6 + c0] = vxy.y;

        __syncthreads();

        // horizontal 11-tap conv: 12-float window -> 2 outputs, 5 fields
        float m[5][2];
#pragma unroll
        for (int f = 0; f < 5; ++f) {
            const float2* row2 = (const float2*)(hb + f * PSTR);
            float2 a  = row2[tid];
            float2 b2 = row2[tid + 1];
            float2 c2 = row2[tid + 2];
            float2 d2 = row2[tid + 3];
            float2 e2 = row2[tid + 4];
            float2 f2 = row2[tid + 5];
            float w[12] = { a.x,  a.y,  b2.x, b2.y, c2.x, c2.y,
                            d2.x, d2.y, e2.x, e2.y, f2.x, f2.y };
            float s0 = 0.f, s1 = 0.f;
#pragma unroll
            for (int k = 0; k < 11; ++k) {
                s0 += win.g[k] * w[k];
                s1 += win.g[k] * w[k + 1];
            }
            m[f][0] = s0;
            m[f][1] = s1;
        }

#pragma unroll
        for (int u = 0; u < 2; ++u) {
            float mx  = m[0][u];
            float my  = m[1][u];
            float mxx = m[2][u];
            float myy = m[3][u];
            float mxy = m[4][u];
            float mu_x_sq = mx * mx;
            float mu_y_sq = my * my;
            float mu_xy   = mx * my;
            float sig_x  = mxx - mu_x_sq;
            float sig_y  = myy - mu_y_sq;
            float sig_xy = mxy - mu_xy;
            const float C1 = 0.01f * 0.01f;
            const float C2 = 0.03f * 0.03f;
            float n = (2.f * mu_xy + C1) * (2.f * sig_xy + C2);
            float d = (mu_x_sq + mu_y_sq + C1) * (sig_x + sig_y + C2);
            lsum += n / (d + 1e-8f);
        }
    }

    // block reduction
#pragma unroll
    for (int off = 32; off; off >>= 1) lsum += __shfl_down(lsum, off);
    if ((tid & 63) == 0) wsum[tid >> 6] = lsum;
    __syncthreads();
    if (tid == 0)
        atomicAdd(accum, (double)(wsum[0] + wsum[1] + wsum[2] + wsum[3]));
}

__global__ void ssim_finalize_kernel(const double* __restrict__ accum,
                                     float* __restrict__ out)
{
    out[0] = (float)(accum[0] / (double)TOTAL_PIX);
}

extern "C" void kernel_launch(void* const* d_in, const int* in_sizes, int n_in,
                              void* d_out, int out_size, void* d_ws, size_t ws_size,
                              hipStream_t stream) {
    const float* x = (const float*)d_in[0];
    const float* y = (const float*)d_in[1];
    float* out = (float*)d_out;
    double* accum = (double*)d_ws;

    GWin win;
    {
        double g[11], s = 0.0;
        for (int i = 0; i < 11; ++i) {
            double d = (double)i - 5.0;
            g[i] = std::exp(-(d * d) / (2.0 * 1.5 * 1.5));
            s += g[i];
        }
        for (int i = 0; i < 11; ++i) win.g[i] = (float)(g[i] / s);
    }

    hipMemsetAsync(d_ws, 0, sizeof(double), stream);

    const int nblocks = PLANES * BANDS;  // 1536
    ssim_stream_kernel<<<nblocks, 256, 0, stream>>>(x, y, accum, win);
    ssim_finalize_kernel<<<1, 1, 0, stream>>>(accum, out);
}